// Round 1
// baseline (1113.440 us; speedup 1.0000x reference)
//
#include <hip/hip_runtime.h>
#include <math.h>

#define NPIX 16384

typedef __bf16 bf16x8 __attribute__((ext_vector_type(8)));
typedef float f32x4 __attribute__((ext_vector_type(4)));
typedef unsigned short u16;
typedef unsigned int u32;

__device__ __forceinline__ u16 f2bf(float f) {
    u32 u = __float_as_uint(f);
    u32 r = (u + 0x7FFFu + ((u >> 16) & 1u)) >> 16;
    return (u16)r;
}
__device__ __forceinline__ float bf2f(u32 s) { return __uint_as_float(s << 16); }
__device__ __forceinline__ u32 pk2(float a, float b) {
    return (u32)f2bf(a) | ((u32)f2bf(b) << 16);
}

// ---------------- K0w: convert weights to bf16 ----------------
__global__ __launch_bounds__(256) void k_cvtw(
    const float* __restrict__ wq, const float* __restrict__ wpw,
    const float* __restrict__ wout,
    u16* __restrict__ wq_b, u16* __restrict__ wpw_b, u16* __restrict__ wout_b)
{
    int id = (blockIdx.x * 256 + threadIdx.x) * 4;
    const float* s; u16* d; int off;
    if (id < 131072)      { s = wq;   d = wq_b;   off = id; }
    else if (id < 393216) { s = wpw;  d = wpw_b;  off = id - 131072; }
    else                  { s = wout; d = wout_b; off = id - 393216; }
    f32x4 v = *(const f32x4*)(s + off);
    uint2 u; u.x = pk2(v[0], v[1]); u.y = pk2(v[2], v[3]);
    *(uint2*)(d + off) = u;
}

// ---------------- K0: depthwise 3x3 conv + transpose to [n][c] bf16 ----------------
__global__ __launch_bounds__(256) void k_conv(
    const float* __restrict__ fmap, const float* __restrict__ wdw,
    u16* __restrict__ fmapT, u16* __restrict__ dwT)
{
    const int t  = threadIdx.x;
    const int ct = blockIdx.x & 3, yt = blockIdx.x >> 2;
    const int x  = blockIdx.y, b = blockIdx.z;
    const int c0 = ct * 64, y0 = yt * 64;
    __shared__ float fs[64 * 65];
    __shared__ float dsh[64 * 65];
    const int y_l = t & 63;
    const int y = y0 + y_l;
    for (int i = 0; i < 16; ++i) {
        const int cl = (t >> 6) * 16 + i;
        const int c = c0 + cl;
        const float* base = fmap + ((size_t)(b * 256 + c)) * NPIX;
        const float* wp = wdw + c * 9;
        float s = 0.f, center = 0.f;
        #pragma unroll
        for (int dx = -1; dx <= 1; ++dx) {
            int xx = x + dx;
            if (xx < 0 || xx > 127) continue;
            #pragma unroll
            for (int dy = -1; dy <= 1; ++dy) {
                int yy = y + dy;
                if (yy < 0 || yy > 127) continue;
                float f = base[xx * 128 + yy];
                s += f * wp[(dx + 1) * 3 + (dy + 1)];
                if (dx == 0 && dy == 0) center = f;
            }
        }
        fs[cl * 65 + y_l] = center;
        dsh[cl * 65 + y_l] = s;
    }
    __syncthreads();
    for (int i = 0; i < 8; ++i) {
        int p = i * 256 + t;
        int yy = p >> 5, cp = (p & 31) * 2;
        size_t row = ((size_t)b * NPIX + x * 128 + y0 + yy) * 256 + c0 + cp;
        *(u32*)(fmapT + row) = pk2(fs[cp * 65 + yy], fs[(cp + 1) * 65 + yy]);
        *(u32*)(dwT + row)   = pk2(dsh[cp * 65 + yy], dsh[(cp + 1) * 65 + yy]);
    }
}

// ---------------- K2: kv projection GEMM; k-half -> exp -> E, v-half -> V ----------------
// D[m=ch 128][n=pix 128] = wpw[ch][c] * dwT[pix][c]^T, K=256
__global__ __launch_bounds__(256) void k_proj_kv(
    const u16* __restrict__ dwT, const u16* __restrict__ wpw,
    u16* __restrict__ E, u16* __restrict__ V)
{
    const int t = threadIdx.x;
    const int lane = t & 63, w = t >> 6;
    const int l15 = lane & 15, quad = lane >> 4;
    const int n0 = blockIdx.x * 128;
    const int o0 = blockIdx.y * 128;
    const int b  = blockIdx.z;
    __shared__ __align__(16) u16 sm[2 * 128 * 72];
    u16* As = sm;
    u16* Bs = sm + 128 * 72;
    f32x4 acc[4][4] = {};
    const int mh = (w >> 1) * 64, nh = (w & 1) * 64;
    const u16* wrow = wpw + (size_t)o0 * 256;
    const u16* xrow = dwT + ((size_t)b * NPIX + n0) * 256;
    for (int kc = 0; kc < 4; ++kc) {
        __syncthreads();
        const int g = t & 7;
        #pragma unroll
        for (int p = 0; p < 4; ++p) {
            int row = (t >> 3) + 32 * p;
            *(uint4*)(As + row * 72 + g * 8) = *(const uint4*)(wrow + (size_t)row * 256 + kc * 64 + g * 8);
            *(uint4*)(Bs + row * 72 + g * 8) = *(const uint4*)(xrow + (size_t)row * 256 + kc * 64 + g * 8);
        }
        __syncthreads();
        #pragma unroll
        for (int kk = 0; kk < 64; kk += 32) {
            bf16x8 av[4], bv[4];
            #pragma unroll
            for (int mf = 0; mf < 4; ++mf)
                av[mf] = *(const bf16x8*)(As + (mh + mf * 16 + l15) * 72 + kk + quad * 8);
            #pragma unroll
            for (int nf = 0; nf < 4; ++nf)
                bv[nf] = *(const bf16x8*)(Bs + (nh + nf * 16 + l15) * 72 + kk + quad * 8);
            #pragma unroll
            for (int mf = 0; mf < 4; ++mf)
                #pragma unroll
                for (int nf = 0; nf < 4; ++nf)
                    acc[mf][nf] = __builtin_amdgcn_mfma_f32_16x16x32_bf16(av[mf], bv[nf], acc[mf][nf], 0, 0, 0);
        }
    }
    __syncthreads();
    const bool isE = (o0 < 512);
    u16* ep = sm;  // [128][136]
    #pragma unroll
    for (int mf = 0; mf < 4; ++mf)
        #pragma unroll
        for (int nf = 0; nf < 4; ++nf)
            #pragma unroll
            for (int r = 0; r < 4; ++r) {
                int row = mh + mf * 16 + quad * 4 + r;
                int col = nh + nf * 16 + l15;
                float vv = acc[mf][nf][r];
                if (isE) vv = expf(vv);
                ep[row * 136 + col] = f2bf(vv);
            }
    __syncthreads();
    u16* outp = isE ? E : V;
    const int cb = isE ? o0 : (o0 - 512);
    for (int p = 0; p < 4; ++p) {
        int row = (t >> 3) + 32 * p;
        size_t base = ((size_t)b * 512 + cb + row) * NPIX + n0;
        int g2 = (t & 7) * 16;
        *(uint4*)(outp + base + g2)     = *(const uint4*)(ep + row * 136 + g2);
        *(uint4*)(outp + base + g2 + 8) = *(const uint4*)(ep + row * 136 + g2 + 8);
    }
}

// ---------------- K3: context ctxT[e][d] = sum_n V[e][n]*E[d][n] (split-K atomics) + denom ----------------
__global__ __launch_bounds__(256) void k_context(
    const u16* __restrict__ E, const u16* __restrict__ V,
    float* __restrict__ ctx, float* __restrict__ denom)
{
    const int t = threadIdx.x;
    const int lane = t & 63, w = t >> 6;
    const int l15 = lane & 15, quad = lane >> 4;
    const int nb = blockIdx.x * 512;
    const int bh = blockIdx.y;
    __shared__ __align__(16) u16 sm[2 * 64 * 136];
    u16* As = sm;
    u16* Bs = sm + 64 * 136;
    __shared__ float dsum[64];
    if (t < 64) dsum[t] = 0.f;
    f32x4 acc[4] = {};
    const u16* Vb = V + (size_t)bh * 64 * NPIX;
    const u16* Eb = E + (size_t)bh * 64 * NPIX;
    for (int cch = 0; cch < 4; ++cch) {
        int ns = nb + cch * 128;
        __syncthreads();
        int g = t & 15;
        #pragma unroll
        for (int p = 0; p < 4; ++p) {
            int row = (t >> 4) + 16 * p;
            *(uint4*)(As + row * 136 + g * 8) = *(const uint4*)(Vb + (size_t)row * NPIX + ns + g * 8);
            *(uint4*)(Bs + row * 136 + g * 8) = *(const uint4*)(Eb + (size_t)row * NPIX + ns + g * 8);
        }
        __syncthreads();
        #pragma unroll
        for (int kk = 0; kk < 128; kk += 32) {
            bf16x8 av = *(const bf16x8*)(As + (w * 16 + l15) * 136 + kk + quad * 8);
            #pragma unroll
            for (int nf = 0; nf < 4; ++nf) {
                bf16x8 bv = *(const bf16x8*)(Bs + (nf * 16 + l15) * 136 + kk + quad * 8);
                acc[nf] = __builtin_amdgcn_mfma_f32_16x16x32_bf16(av, bv, acc[nf], 0, 0, 0);
            }
        }
    }
    #pragma unroll
    for (int nf = 0; nf < 4; ++nf)
        #pragma unroll
        for (int r = 0; r < 4; ++r) {
            int e = w * 16 + quad * 4 + r;
            int d = nf * 16 + l15;
            atomicAdd(ctx + ((size_t)bh * 64 + e) * 64 + d, acc[nf][r]);
        }
    // denominator partials over this block's n-slice
    for (int d = 0; d < 64; ++d) {
        u32 u = *(const u32*)(Eb + (size_t)d * NPIX + nb + t * 2);
        float s = bf2f(u & 0xFFFFu) + bf2f(u >> 16);
        s += __shfl_xor(s, 1);  s += __shfl_xor(s, 2);  s += __shfl_xor(s, 4);
        s += __shfl_xor(s, 8);  s += __shfl_xor(s, 16); s += __shfl_xor(s, 32);
        if (lane == 0) atomicAdd(dsum + d, s);
    }
    __syncthreads();
    if (t < 64) atomicAdd(denom + bh * 64 + t, dsum[t]);
}

// ---------------- K1: q projection GEMM + fused per-(pixel,head) softmax * 1/8 ----------------
__global__ __launch_bounds__(256) void k_proj_q(
    const u16* __restrict__ fmapT, const u16* __restrict__ wq,
    u16* __restrict__ q)
{
    const int t = threadIdx.x;
    const int lane = t & 63, w = t >> 6;
    const int l15 = lane & 15, quad = lane >> 4;
    const int n0 = blockIdx.x * 128;
    const int o0 = blockIdx.y * 128;
    const int b  = blockIdx.z;
    __shared__ __align__(16) unsigned char smraw[71680];
    u16* As = (u16*)smraw;
    u16* Bs = As + 128 * 72;
    f32x4 acc[4][4] = {};
    const int mh = (w >> 1) * 64, nh = (w & 1) * 64;
    const u16* wrow = wq + (size_t)o0 * 256;
    const u16* xrow = fmapT + ((size_t)b * NPIX + n0) * 256;
    for (int kc = 0; kc < 4; ++kc) {
        __syncthreads();
        const int g = t & 7;
        #pragma unroll
        for (int p = 0; p < 4; ++p) {
            int row = (t >> 3) + 32 * p;
            *(uint4*)(As + row * 72 + g * 8) = *(const uint4*)(wrow + (size_t)row * 256 + kc * 64 + g * 8);
            *(uint4*)(Bs + row * 72 + g * 8) = *(const uint4*)(xrow + (size_t)row * 256 + kc * 64 + g * 8);
        }
        __syncthreads();
        #pragma unroll
        for (int kk = 0; kk < 64; kk += 32) {
            bf16x8 av[4], bv[4];
            #pragma unroll
            for (int mf = 0; mf < 4; ++mf)
                av[mf] = *(const bf16x8*)(As + (mh + mf * 16 + l15) * 72 + kk + quad * 8);
            #pragma unroll
            for (int nf = 0; nf < 4; ++nf)
                bv[nf] = *(const bf16x8*)(Bs + (nh + nf * 16 + l15) * 72 + kk + quad * 8);
            #pragma unroll
            for (int mf = 0; mf < 4; ++mf)
                #pragma unroll
                for (int nf = 0; nf < 4; ++nf)
                    acc[mf][nf] = __builtin_amdgcn_mfma_f32_16x16x32_bf16(av[mf], bv[nf], acc[mf][nf], 0, 0, 0);
        }
    }
    __syncthreads();
    float* ep = (float*)smraw;  // [128 pix][140] fp32 logits, transposed
    #pragma unroll
    for (int mf = 0; mf < 4; ++mf)
        #pragma unroll
        for (int nf = 0; nf < 4; ++nf)
            #pragma unroll
            for (int r = 0; r < 4; ++r) {
                int row = mh + mf * 16 + quad * 4 + r;  // local channel 0..127
                int col = nh + nf * 16 + l15;           // pixel
                ep[col * 140 + row] = acc[mf][nf][r];
            }
    __syncthreads();
    const int h0 = blockIdx.y * 2;
    for (int p = 0; p < 8; ++p) {
        int unit = p * 32 + (t >> 3);
        int pix = unit >> 1, hh = unit & 1;
        int d8 = (t & 7) * 8;
        f32x4 v0 = *(const f32x4*)(ep + pix * 140 + hh * 64 + d8);
        f32x4 v1 = *(const f32x4*)(ep + pix * 140 + hh * 64 + d8 + 4);
        float e0 = expf(v0[0]), e1 = expf(v0[1]), e2 = expf(v0[2]), e3 = expf(v0[3]);
        float e4 = expf(v1[0]), e5 = expf(v1[1]), e6 = expf(v1[2]), e7 = expf(v1[3]);
        float s = ((e0 + e1) + (e2 + e3)) + ((e4 + e5) + (e6 + e7));
        s += __shfl_xor(s, 1); s += __shfl_xor(s, 2); s += __shfl_xor(s, 4);
        float r = 0.125f / s;
        uint4 u;
        u.x = pk2(e0 * r, e1 * r); u.y = pk2(e2 * r, e3 * r);
        u.z = pk2(e4 * r, e5 * r); u.w = pk2(e6 * r, e7 * r);
        size_t off = (((size_t)b * 8 + h0 + hh) * NPIX + n0 + pix) * 64 + d8;
        *(uint4*)(q + off) = u;
    }
}

// ---------------- K4: out = (gelu(q @ ctx_norm)) @ w_out^T + b ----------------
__global__ __launch_bounds__(256) void k_attnout(
    const u16* __restrict__ q, const float* __restrict__ ctx,
    const float* __restrict__ denom, const u16* __restrict__ wout,
    const float* __restrict__ bout, float* __restrict__ out)
{
    const int t = threadIdx.x;
    const int lane = t & 63, w = t >> 6;
    const int l15 = lane & 15, quad = lane >> 4;
    const int n0 = blockIdx.x * 32;
    const int b  = blockIdx.y;
    __shared__ __align__(16) u16 tmp[32 * 520];
    __shared__ __align__(16) unsigned char R[20480];
    u16* qs = (u16*)R;            // [32][72]
    u16* cs = (u16*)(R + 4608);   // [64][72]
    u16* ws = (u16*)R;            // [256][40] (reused after head loop)
    for (int h = 0; h < 8; ++h) {
        __syncthreads();
        {
            int row = t >> 3, g = t & 7;
            *(uint4*)(qs + row * 72 + g * 8) =
                *(const uint4*)(q + (((size_t)b * 8 + h) * NPIX + n0 + row) * 64 + g * 8);
        }
        const int bh = b * 8 + h;
        #pragma unroll
        for (int p = 0; p < 4; ++p) {
            int idx = p * 256 + t;
            int e = idx >> 4, dq = (idx & 15) * 4;
            f32x4 c4 = *(const f32x4*)(ctx + ((size_t)bh * 64 + e) * 64 + dq);
            f32x4 d4 = *(const f32x4*)(denom + bh * 64 + dq);
            uint2 u;
            u.x = pk2(c4[0] / d4[0], c4[1] / d4[1]);
            u.y = pk2(c4[2] / d4[2], c4[3] / d4[3]);
            *(uint2*)(cs + e * 72 + dq) = u;
        }
        __syncthreads();
        f32x4 a1[2] = {};
        #pragma unroll
        for (int kk = 0; kk < 64; kk += 32) {
            bf16x8 av = *(const bf16x8*)(qs + ((w & 1) * 16 + l15) * 72 + kk + quad * 8);
            #pragma unroll
            for (int j = 0; j < 2; ++j) {
                int nf = (w >> 1) * 2 + j;
                bf16x8 bv = *(const bf16x8*)(cs + (nf * 16 + l15) * 72 + kk + quad * 8);
                a1[j] = __builtin_amdgcn_mfma_f32_16x16x32_bf16(av, bv, a1[j], 0, 0, 0);
            }
        }
        #pragma unroll
        for (int j = 0; j < 2; ++j)
            #pragma unroll
            for (int r = 0; r < 4; ++r) {
                int pix = (w & 1) * 16 + quad * 4 + r;
                int e = ((w >> 1) * 2 + j) * 16 + l15;
                float x = a1[j][r];
                float gel = 0.5f * x * (1.0f + erff(x * 0.70710678118654752f));
                tmp[pix * 520 + h * 64 + e] = f2bf(gel);
            }
    }
    __syncthreads();
    f32x4 acc[4][2] = {};
    for (int kc = 0; kc < 16; ++kc) {
        __syncthreads();
        #pragma unroll
        for (int p = 0; p < 4; ++p) {
            int c = (t >> 2) + 64 * p, g = t & 3;
            *(uint4*)(ws + c * 40 + g * 8) = *(const uint4*)(wout + (size_t)c * 512 + kc * 32 + g * 8);
        }
        __syncthreads();
        bf16x8 av[4], bv[2];
        #pragma unroll
        for (int mf = 0; mf < 4; ++mf)
            av[mf] = *(const bf16x8*)(ws + (w * 64 + mf * 16 + l15) * 40 + quad * 8);
        #pragma unroll
        for (int nf = 0; nf < 2; ++nf)
            bv[nf] = *(const bf16x8*)(tmp + (nf * 16 + l15) * 520 + kc * 32 + quad * 8);
        #pragma unroll
        for (int mf = 0; mf < 4; ++mf)
            #pragma unroll
            for (int nf = 0; nf < 2; ++nf)
                acc[mf][nf] = __builtin_amdgcn_mfma_f32_16x16x32_bf16(av[mf], bv[nf], acc[mf][nf], 0, 0, 0);
    }
    #pragma unroll
    for (int mf = 0; mf < 4; ++mf)
        #pragma unroll
        for (int nf = 0; nf < 2; ++nf)
            #pragma unroll
            for (int r = 0; r < 4; ++r) {
                int c = w * 64 + mf * 16 + quad * 4 + r;
                int pix = nf * 16 + l15;
                out[((size_t)b * 256 + c) * NPIX + n0 + pix] = acc[mf][nf][r] + bout[c];
            }
}

extern "C" void kernel_launch(void* const* d_in, const int* in_sizes, int n_in,
                              void* d_out, int out_size, void* d_ws, size_t ws_size,
                              hipStream_t stream)
{
    const float* fmap  = (const float*)d_in[0];
    const float* w_q   = (const float*)d_in[1];
    const float* w_dw  = (const float*)d_in[2];
    const float* w_pw  = (const float*)d_in[3];
    const float* w_out = (const float*)d_in[4];
    const float* b_out = (const float*)d_in[5];
    float* out = (float*)d_out;
    char* ws = (char*)d_ws;

    u16* dwT     = (u16*)(ws);                  // 67,108,864 B  [8][16384][256]
    u16* fmapT   = (u16*)(ws + 67108864);       // 67,108,864 B
    u16* E       = (u16*)(ws + 134217728);      // 134,217,728 B [8][512][16384]
    u16* V       = (u16*)(ws + 268435456);      // 134,217,728 B
    u16* q       = (u16*)(ws + 134217728);      // overlaps E (dead after k_context)
    float* ctx   = (float*)(ws + 402653184);    // 1,048,576 B  [64][64][64]
    float* denom = (float*)(ws + 403701760);    // 16,384 B
    u16* wq_b    = (u16*)(ws + 403718144);      // 262,144 B
    u16* wpw_b   = (u16*)(ws + 403980288);      // 524,288 B
    u16* wout_b  = (u16*)(ws + 404504576);      // 262,144 B
    // total workspace: 404,766,720 B

    hipMemsetAsync(ws + 402653184, 0, 1048576 + 16384, stream);
    k_cvtw<<<512, 256, 0, stream>>>(w_q, w_pw, w_out, wq_b, wpw_b, wout_b);
    k_conv<<<dim3(8, 128, 8), 256, 0, stream>>>(fmap, w_dw, fmapT, dwT);
    k_proj_kv<<<dim3(128, 8, 8), 256, 0, stream>>>(dwT, wpw_b, E, V);
    k_context<<<dim3(32, 64), 256, 0, stream>>>(E, V, ctx, denom);
    k_proj_q<<<dim3(128, 4, 8), 256, 0, stream>>>(fmapT, wq_b, q);  // q overlaps E: must run after k_context
    k_attnout<<<dim3(512, 8), 256, 0, stream>>>(q, ctx, denom, wout_b, b_out, out);
}

// Round 2
// 1110.031 us; speedup vs baseline: 1.0031x; 1.0031x over previous
//
#include <hip/hip_runtime.h>
#include <math.h>

#define NPIX 16384

typedef __bf16 bf16x8 __attribute__((ext_vector_type(8)));
typedef float f32x4 __attribute__((ext_vector_type(4)));
typedef unsigned short u16;
typedef unsigned int u32;

__device__ __forceinline__ u16 f2bf(float f) {
    u32 u = __float_as_uint(f);
    u32 r = (u + 0x7FFFu + ((u >> 16) & 1u)) >> 16;
    return (u16)r;
}
__device__ __forceinline__ float bf2f(u32 s) { return __uint_as_float(s << 16); }
__device__ __forceinline__ u32 pk2(float a, float b) {
    return (u32)f2bf(a) | ((u32)f2bf(b) << 16);
}

// ---------------- K0w: convert weights to bf16 ----------------
__global__ __launch_bounds__(256) void k_cvtw(
    const float* __restrict__ wq, const float* __restrict__ wpw,
    const float* __restrict__ wout,
    u16* __restrict__ wq_b, u16* __restrict__ wpw_b, u16* __restrict__ wout_b)
{
    int id = (blockIdx.x * 256 + threadIdx.x) * 4;
    const float* s; u16* d; int off;
    if (id < 131072)      { s = wq;   d = wq_b;   off = id; }
    else if (id < 393216) { s = wpw;  d = wpw_b;  off = id - 131072; }
    else                  { s = wout; d = wout_b; off = id - 393216; }
    f32x4 v = *(const f32x4*)(s + off);
    uint2 u; u.x = pk2(v[0], v[1]); u.y = pk2(v[2], v[3]);
    *(uint2*)(d + off) = u;
}

// ---------------- K0: depthwise 3x3 conv + transpose to [n][c] bf16 ----------------
// Block = (x row, y-half, batch), covers ALL 256 channels.
// lane = y (coalesced loads); branch-free y-edges (clamped idx * mask);
// uniform x-edge branches; LDS-staged transpose; 1KB-coalesced uint4 writes.
__global__ __launch_bounds__(256) void k_conv(
    const float* __restrict__ fmap, const float* __restrict__ wdw,
    u16* __restrict__ fmapT, u16* __restrict__ dwT)
{
    const int t = threadIdx.x;
    const int lane = t & 63, w = t >> 6;
    const int x = blockIdx.x, yh = blockIdx.y, b = blockIdx.z;

    __shared__ u16 dst[2][64][258];   // [tensor][y][c], stride 258 u16 = odd dwords
    __shared__ float wlds[2304];      // 256 ch x 9 taps

    for (int i = t; i < 2304; i += 256) wlds[i] = wdw[i];
    __syncthreads();

    const int y = yh * 64 + lane;
    const float mL = (y == 0) ? 0.f : 1.f;
    const float mR = (y == 127) ? 0.f : 1.f;
    const int yl = y - (y > 0 ? 1 : 0);
    const int yr = y + (y < 127 ? 1 : 0);
    const bool hasT = (x > 0), hasB = (x < 127);

    const int c0 = w * 64;
    const float* base = fmap + ((size_t)b * 256 + c0) * NPIX + (size_t)x * 128;
    const float* wc = wlds + c0 * 9;

    #pragma unroll 2
    for (int ci = 0; ci < 64; ++ci) {
        float acc, center;
        {
            const float* r = base;
            float a = r[yl] * mL, m = r[y], c2 = r[yr] * mR;
            center = m;
            acc = a * wc[3] + m * wc[4] + c2 * wc[5];
        }
        if (hasT) {
            const float* r = base - 128;
            acc += r[yl] * mL * wc[0] + r[y] * wc[1] + r[yr] * mR * wc[2];
        }
        if (hasB) {
            const float* r = base + 128;
            acc += r[yl] * mL * wc[6] + r[y] * wc[7] + r[yr] * mR * wc[8];
        }
        dst[0][lane][c0 + ci] = f2bf(center);
        dst[1][lane][c0 + ci] = f2bf(acc);
        base += NPIX;
        wc += 9;
    }
    __syncthreads();

    // write-out: per pixel row, 256 c * 2B = 512B contiguous; wave = 1KB
    const size_t nbase = (size_t)b * NPIX + (size_t)x * 128 + yh * 64;
    #pragma unroll
    for (int T = 0; T < 2; ++T) {
        const u16* src = &dst[T][0][0];
        u16* g = T ? dwT : fmapT;
        #pragma unroll
        for (int i = 0; i < 8; ++i) {
            int row = i * 8 + (t >> 5);
            int cg = (t & 31) * 8;
            const u16* s = src + row * 258 + cg;
            uint4 u;
            u.x = *(const u32*)(s);
            u.y = *(const u32*)(s + 2);
            u.z = *(const u32*)(s + 4);
            u.w = *(const u32*)(s + 6);
            *(uint4*)(g + (nbase + row) * 256 + cg) = u;
        }
    }
}

// ---------------- K2: kv projection GEMM; k-half -> exp -> E, v-half -> V ----------------
// D[m=ch 128][n=pix 128] = wpw[ch][c] * dwT[pix][c]^T, K=256
__global__ __launch_bounds__(256) void k_proj_kv(
    const u16* __restrict__ dwT, const u16* __restrict__ wpw,
    u16* __restrict__ E, u16* __restrict__ V)
{
    const int t = threadIdx.x;
    const int lane = t & 63, w = t >> 6;
    const int l15 = lane & 15, quad = lane >> 4;
    const int n0 = blockIdx.x * 128;
    const int o0 = blockIdx.y * 128;
    const int b  = blockIdx.z;
    __shared__ __align__(16) u16 sm[2 * 128 * 72];
    u16* As = sm;
    u16* Bs = sm + 128 * 72;
    f32x4 acc[4][4] = {};
    const int mh = (w >> 1) * 64, nh = (w & 1) * 64;
    const u16* wrow = wpw + (size_t)o0 * 256;
    const u16* xrow = dwT + ((size_t)b * NPIX + n0) * 256;
    for (int kc = 0; kc < 4; ++kc) {
        __syncthreads();
        const int g = t & 7;
        #pragma unroll
        for (int p = 0; p < 4; ++p) {
            int row = (t >> 3) + 32 * p;
            *(uint4*)(As + row * 72 + g * 8) = *(const uint4*)(wrow + (size_t)row * 256 + kc * 64 + g * 8);
            *(uint4*)(Bs + row * 72 + g * 8) = *(const uint4*)(xrow + (size_t)row * 256 + kc * 64 + g * 8);
        }
        __syncthreads();
        #pragma unroll
        for (int kk = 0; kk < 64; kk += 32) {
            bf16x8 av[4], bv[4];
            #pragma unroll
            for (int mf = 0; mf < 4; ++mf)
                av[mf] = *(const bf16x8*)(As + (mh + mf * 16 + l15) * 72 + kk + quad * 8);
            #pragma unroll
            for (int nf = 0; nf < 4; ++nf)
                bv[nf] = *(const bf16x8*)(Bs + (nh + nf * 16 + l15) * 72 + kk + quad * 8);
            #pragma unroll
            for (int mf = 0; mf < 4; ++mf)
                #pragma unroll
                for (int nf = 0; nf < 4; ++nf)
                    acc[mf][nf] = __builtin_amdgcn_mfma_f32_16x16x32_bf16(av[mf], bv[nf], acc[mf][nf], 0, 0, 0);
        }
    }
    __syncthreads();
    const bool isE = (o0 < 512);
    u16* ep = sm;  // [128][136]
    #pragma unroll
    for (int mf = 0; mf < 4; ++mf)
        #pragma unroll
        for (int nf = 0; nf < 4; ++nf)
            #pragma unroll
            for (int r = 0; r < 4; ++r) {
                int row = mh + mf * 16 + quad * 4 + r;
                int col = nh + nf * 16 + l15;
                float vv = acc[mf][nf][r];
                if (isE) vv = expf(vv);
                ep[row * 136 + col] = f2bf(vv);
            }
    __syncthreads();
    u16* outp = isE ? E : V;
    const int cb = isE ? o0 : (o0 - 512);
    for (int p = 0; p < 4; ++p) {
        int row = (t >> 3) + 32 * p;
        size_t base = ((size_t)b * 512 + cb + row) * NPIX + n0;
        int g2 = (t & 7) * 16;
        *(uint4*)(outp + base + g2)     = *(const uint4*)(ep + row * 136 + g2);
        *(uint4*)(outp + base + g2 + 8) = *(const uint4*)(ep + row * 136 + g2 + 8);
    }
}

// ---------------- K3: context ctxT[e][d] = sum_n V[e][n]*E[d][n] (split-K atomics) + denom ----------------
__global__ __launch_bounds__(256) void k_context(
    const u16* __restrict__ E, const u16* __restrict__ V,
    float* __restrict__ ctx, float* __restrict__ denom)
{
    const int t = threadIdx.x;
    const int lane = t & 63, w = t >> 6;
    const int l15 = lane & 15, quad = lane >> 4;
    const int nb = blockIdx.x * 512;
    const int bh = blockIdx.y;
    __shared__ __align__(16) u16 sm[2 * 64 * 136];
    u16* As = sm;
    u16* Bs = sm + 64 * 136;
    __shared__ float dsum[64];
    if (t < 64) dsum[t] = 0.f;
    f32x4 acc[4] = {};
    const u16* Vb = V + (size_t)bh * 64 * NPIX;
    const u16* Eb = E + (size_t)bh * 64 * NPIX;
    for (int cch = 0; cch < 4; ++cch) {
        int ns = nb + cch * 128;
        __syncthreads();
        int g = t & 15;
        #pragma unroll
        for (int p = 0; p < 4; ++p) {
            int row = (t >> 4) + 16 * p;
            *(uint4*)(As + row * 136 + g * 8) = *(const uint4*)(Vb + (size_t)row * NPIX + ns + g * 8);
            *(uint4*)(Bs + row * 136 + g * 8) = *(const uint4*)(Eb + (size_t)row * NPIX + ns + g * 8);
        }
        __syncthreads();
        #pragma unroll
        for (int kk = 0; kk < 128; kk += 32) {
            bf16x8 av = *(const bf16x8*)(As + (w * 16 + l15) * 136 + kk + quad * 8);
            #pragma unroll
            for (int nf = 0; nf < 4; ++nf) {
                bf16x8 bv = *(const bf16x8*)(Bs + (nf * 16 + l15) * 136 + kk + quad * 8);
                acc[nf] = __builtin_amdgcn_mfma_f32_16x16x32_bf16(av, bv, acc[nf], 0, 0, 0);
            }
        }
    }
    #pragma unroll
    for (int nf = 0; nf < 4; ++nf)
        #pragma unroll
        for (int r = 0; r < 4; ++r) {
            int e = w * 16 + quad * 4 + r;
            int d = nf * 16 + l15;
            atomicAdd(ctx + ((size_t)bh * 64 + e) * 64 + d, acc[nf][r]);
        }
    // denominator partials over this block's n-slice
    for (int d = 0; d < 64; ++d) {
        u32 u = *(const u32*)(Eb + (size_t)d * NPIX + nb + t * 2);
        float s = bf2f(u & 0xFFFFu) + bf2f(u >> 16);
        s += __shfl_xor(s, 1);  s += __shfl_xor(s, 2);  s += __shfl_xor(s, 4);
        s += __shfl_xor(s, 8);  s += __shfl_xor(s, 16); s += __shfl_xor(s, 32);
        if (lane == 0) atomicAdd(dsum + d, s);
    }
    __syncthreads();
    if (t < 64) atomicAdd(denom + bh * 64 + t, dsum[t]);
}

// ---------------- K1: q projection GEMM + fused per-(pixel,head) softmax * 1/8 ----------------
__global__ __launch_bounds__(256) void k_proj_q(
    const u16* __restrict__ fmapT, const u16* __restrict__ wq,
    u16* __restrict__ q)
{
    const int t = threadIdx.x;
    const int lane = t & 63, w = t >> 6;
    const int l15 = lane & 15, quad = lane >> 4;
    const int n0 = blockIdx.x * 128;
    const int o0 = blockIdx.y * 128;
    const int b  = blockIdx.z;
    __shared__ __align__(16) unsigned char smraw[71680];
    u16* As = (u16*)smraw;
    u16* Bs = As + 128 * 72;
    f32x4 acc[4][4] = {};
    const int mh = (w >> 1) * 64, nh = (w & 1) * 64;
    const u16* wrow = wq + (size_t)o0 * 256;
    const u16* xrow = fmapT + ((size_t)b * NPIX + n0) * 256;
    for (int kc = 0; kc < 4; ++kc) {
        __syncthreads();
        const int g = t & 7;
        #pragma unroll
        for (int p = 0; p < 4; ++p) {
            int row = (t >> 3) + 32 * p;
            *(uint4*)(As + row * 72 + g * 8) = *(const uint4*)(wrow + (size_t)row * 256 + kc * 64 + g * 8);
            *(uint4*)(Bs + row * 72 + g * 8) = *(const uint4*)(xrow + (size_t)row * 256 + kc * 64 + g * 8);
        }
        __syncthreads();
        #pragma unroll
        for (int kk = 0; kk < 64; kk += 32) {
            bf16x8 av[4], bv[4];
            #pragma unroll
            for (int mf = 0; mf < 4; ++mf)
                av[mf] = *(const bf16x8*)(As + (mh + mf * 16 + l15) * 72 + kk + quad * 8);
            #pragma unroll
            for (int nf = 0; nf < 4; ++nf)
                bv[nf] = *(const bf16x8*)(Bs + (nh + nf * 16 + l15) * 72 + kk + quad * 8);
            #pragma unroll
            for (int mf = 0; mf < 4; ++mf)
                #pragma unroll
                for (int nf = 0; nf < 4; ++nf)
                    acc[mf][nf] = __builtin_amdgcn_mfma_f32_16x16x32_bf16(av[mf], bv[nf], acc[mf][nf], 0, 0, 0);
        }
    }
    __syncthreads();
    float* ep = (float*)smraw;  // [128 pix][140] fp32 logits, transposed
    #pragma unroll
    for (int mf = 0; mf < 4; ++mf)
        #pragma unroll
        for (int nf = 0; nf < 4; ++nf)
            #pragma unroll
            for (int r = 0; r < 4; ++r) {
                int row = mh + mf * 16 + quad * 4 + r;  // local channel 0..127
                int col = nh + nf * 16 + l15;           // pixel
                ep[col * 140 + row] = acc[mf][nf][r];
            }
    __syncthreads();
    const int h0 = blockIdx.y * 2;
    for (int p = 0; p < 8; ++p) {
        int unit = p * 32 + (t >> 3);
        int pix = unit >> 1, hh = unit & 1;
        int d8 = (t & 7) * 8;
        f32x4 v0 = *(const f32x4*)(ep + pix * 140 + hh * 64 + d8);
        f32x4 v1 = *(const f32x4*)(ep + pix * 140 + hh * 64 + d8 + 4);
        float e0 = expf(v0[0]), e1 = expf(v0[1]), e2 = expf(v0[2]), e3 = expf(v0[3]);
        float e4 = expf(v1[0]), e5 = expf(v1[1]), e6 = expf(v1[2]), e7 = expf(v1[3]);
        float s = ((e0 + e1) + (e2 + e3)) + ((e4 + e5) + (e6 + e7));
        s += __shfl_xor(s, 1); s += __shfl_xor(s, 2); s += __shfl_xor(s, 4);
        float r = 0.125f / s;
        uint4 u;
        u.x = pk2(e0 * r, e1 * r); u.y = pk2(e2 * r, e3 * r);
        u.z = pk2(e4 * r, e5 * r); u.w = pk2(e6 * r, e7 * r);
        size_t off = (((size_t)b * 8 + h0 + hh) * NPIX + n0 + pix) * 64 + d8;
        *(uint4*)(q + off) = u;
    }
}

// ---------------- K4: out = (gelu(q @ ctx_norm)) @ w_out^T + b ----------------
__global__ __launch_bounds__(256) void k_attnout(
    const u16* __restrict__ q, const float* __restrict__ ctx,
    const float* __restrict__ denom, const u16* __restrict__ wout,
    const float* __restrict__ bout, float* __restrict__ out)
{
    const int t = threadIdx.x;
    const int lane = t & 63, w = t >> 6;
    const int l15 = lane & 15, quad = lane >> 4;
    const int n0 = blockIdx.x * 32;
    const int b  = blockIdx.y;
    __shared__ __align__(16) u16 tmp[32 * 520];
    __shared__ __align__(16) unsigned char R[20480];
    u16* qs = (u16*)R;            // [32][72]
    u16* cs = (u16*)(R + 4608);   // [64][72]
    u16* ws = (u16*)R;            // [256][40] (reused after head loop)
    for (int h = 0; h < 8; ++h) {
        __syncthreads();
        {
            int row = t >> 3, g = t & 7;
            *(uint4*)(qs + row * 72 + g * 8) =
                *(const uint4*)(q + (((size_t)b * 8 + h) * NPIX + n0 + row) * 64 + g * 8);
        }
        const int bh = b * 8 + h;
        #pragma unroll
        for (int p = 0; p < 4; ++p) {
            int idx = p * 256 + t;
            int e = idx >> 4, dq = (idx & 15) * 4;
            f32x4 c4 = *(const f32x4*)(ctx + ((size_t)bh * 64 + e) * 64 + dq);
            f32x4 d4 = *(const f32x4*)(denom + bh * 64 + dq);
            uint2 u;
            u.x = pk2(c4[0] / d4[0], c4[1] / d4[1]);
            u.y = pk2(c4[2] / d4[2], c4[3] / d4[3]);
            *(uint2*)(cs + e * 72 + dq) = u;
        }
        __syncthreads();
        f32x4 a1[2] = {};
        #pragma unroll
        for (int kk = 0; kk < 64; kk += 32) {
            bf16x8 av = *(const bf16x8*)(qs + ((w & 1) * 16 + l15) * 72 + kk + quad * 8);
            #pragma unroll
            for (int j = 0; j < 2; ++j) {
                int nf = (w >> 1) * 2 + j;
                bf16x8 bv = *(const bf16x8*)(cs + (nf * 16 + l15) * 72 + kk + quad * 8);
                a1[j] = __builtin_amdgcn_mfma_f32_16x16x32_bf16(av, bv, a1[j], 0, 0, 0);
            }
        }
        #pragma unroll
        for (int j = 0; j < 2; ++j)
            #pragma unroll
            for (int r = 0; r < 4; ++r) {
                int pix = (w & 1) * 16 + quad * 4 + r;
                int e = ((w >> 1) * 2 + j) * 16 + l15;
                float x = a1[j][r];
                float gel = 0.5f * x * (1.0f + erff(x * 0.70710678118654752f));
                tmp[pix * 520 + h * 64 + e] = f2bf(gel);
            }
    }
    __syncthreads();
    f32x4 acc[4][2] = {};
    for (int kc = 0; kc < 16; ++kc) {
        __syncthreads();
        #pragma unroll
        for (int p = 0; p < 4; ++p) {
            int c = (t >> 2) + 64 * p, g = t & 3;
            *(uint4*)(ws + c * 40 + g * 8) = *(const uint4*)(wout + (size_t)c * 512 + kc * 32 + g * 8);
        }
        __syncthreads();
        bf16x8 av[4], bv[2];
        #pragma unroll
        for (int mf = 0; mf < 4; ++mf)
            av[mf] = *(const bf16x8*)(ws + (w * 64 + mf * 16 + l15) * 40 + quad * 8);
        #pragma unroll
        for (int nf = 0; nf < 2; ++nf)
            bv[nf] = *(const bf16x8*)(tmp + (nf * 16 + l15) * 520 + kc * 32 + quad * 8);
        #pragma unroll
        for (int mf = 0; mf < 4; ++mf)
            #pragma unroll
            for (int nf = 0; nf < 2; ++nf)
                acc[mf][nf] = __builtin_amdgcn_mfma_f32_16x16x32_bf16(av[mf], bv[nf], acc[mf][nf], 0, 0, 0);
    }
    #pragma unroll
    for (int mf = 0; mf < 4; ++mf)
        #pragma unroll
        for (int nf = 0; nf < 2; ++nf)
            #pragma unroll
            for (int r = 0; r < 4; ++r) {
                int c = w * 64 + mf * 16 + quad * 4 + r;
                int pix = nf * 16 + l15;
                out[((size_t)b * 256 + c) * NPIX + n0 + pix] = acc[mf][nf][r] + bout[c];
            }
}

extern "C" void kernel_launch(void* const* d_in, const int* in_sizes, int n_in,
                              void* d_out, int out_size, void* d_ws, size_t ws_size,
                              hipStream_t stream)
{
    const float* fmap  = (const float*)d_in[0];
    const float* w_q   = (const float*)d_in[1];
    const float* w_dw  = (const float*)d_in[2];
    const float* w_pw  = (const float*)d_in[3];
    const float* w_out = (const float*)d_in[4];
    const float* b_out = (const float*)d_in[5];
    float* out = (float*)d_out;
    char* ws = (char*)d_ws;

    u16* dwT     = (u16*)(ws);                  // 67,108,864 B  [8][16384][256]
    u16* fmapT   = (u16*)(ws + 67108864);       // 67,108,864 B
    u16* E       = (u16*)(ws + 134217728);      // 134,217,728 B [8][512][16384]
    u16* V       = (u16*)(ws + 268435456);      // 134,217,728 B
    u16* q       = (u16*)(ws + 134217728);      // overlaps E (dead after k_context)
    float* ctx   = (float*)(ws + 402653184);    // 1,048,576 B  [64][64][64]
    float* denom = (float*)(ws + 403701760);    // 16,384 B
    u16* wq_b    = (u16*)(ws + 403718144);      // 262,144 B
    u16* wpw_b   = (u16*)(ws + 403980288);      // 524,288 B
    u16* wout_b  = (u16*)(ws + 404504576);      // 262,144 B
    // total workspace: 404,766,720 B

    hipMemsetAsync(ws + 402653184, 0, 1048576 + 16384, stream);
    k_cvtw<<<512, 256, 0, stream>>>(w_q, w_pw, w_out, wq_b, wpw_b, wout_b);
    k_conv<<<dim3(128, 2, 8), 256, 0, stream>>>(fmap, w_dw, fmapT, dwT);
    k_proj_kv<<<dim3(128, 8, 8), 256, 0, stream>>>(dwT, wpw_b, E, V);
    k_context<<<dim3(32, 64), 256, 0, stream>>>(E, V, ctx, denom);
    k_proj_q<<<dim3(128, 4, 8), 256, 0, stream>>>(fmapT, wq_b, q);  // q overlaps E: must run after k_context
    k_attnout<<<dim3(512, 8), 256, 0, stream>>>(q, ctx, denom, wout_b, b_out, out);
}

// Round 3
// 897.234 us; speedup vs baseline: 1.2410x; 1.2372x over previous
//
#include <hip/hip_runtime.h>
#include <math.h>

#define NPIX 16384

typedef __bf16 bf16x8 __attribute__((ext_vector_type(8)));
typedef float f32x4 __attribute__((ext_vector_type(4)));
typedef unsigned short u16;
typedef unsigned int u32;

__device__ __forceinline__ u16 f2bf(float f) {
    u32 u = __float_as_uint(f);
    u32 r = (u + 0x7FFFu + ((u >> 16) & 1u)) >> 16;
    return (u16)r;
}
__device__ __forceinline__ float bf2f(u32 s) { return __uint_as_float(s << 16); }
__device__ __forceinline__ u32 pk2(float a, float b) {
    return (u32)f2bf(a) | ((u32)f2bf(b) << 16);
}

// ---------------- K0w: convert weights to bf16 ----------------
__global__ __launch_bounds__(256) void k_cvtw(
    const float* __restrict__ wq, const float* __restrict__ wpw,
    const float* __restrict__ wout,
    u16* __restrict__ wq_b, u16* __restrict__ wpw_b, u16* __restrict__ wout_b)
{
    int id = (blockIdx.x * 256 + threadIdx.x) * 4;
    const float* s; u16* d; int off;
    if (id < 131072)      { s = wq;   d = wq_b;   off = id; }
    else if (id < 393216) { s = wpw;  d = wpw_b;  off = id - 131072; }
    else                  { s = wout; d = wout_b; off = id - 393216; }
    f32x4 v = *(const f32x4*)(s + off);
    uint2 u; u.x = pk2(v[0], v[1]); u.y = pk2(v[2], v[3]);
    *(uint2*)(d + off) = u;
}

// ---------------- K0: depthwise 3x3 conv + transpose to [n][c] bf16 ----------------
// Block = (x, b). Lane covers y = {2*lane, 2*lane+1} via float2 loads.
// 3 loads/channel (y-neighbors via shuffles), 12 loads issued per 4-channel
// batch before compute (MLP). x-edges: clamped pointer + weight masks.
// Output staged in LDS per 64-channel chunk, written as uint4 (128B/pixel chunks).
__global__ __launch_bounds__(256) void k_conv(
    const float* __restrict__ fmap, const float* __restrict__ wdw,
    u16* __restrict__ fmapT, u16* __restrict__ dwT)
{
    const int t = threadIdx.x;
    const int lane = t & 63, w = t >> 6;
    const int x = blockIdx.x, b = blockIdx.y;

    __shared__ u16 dst[2][128][66];   // 33,792 B -> 4 blocks/CU

    const float mLf = (lane == 0) ? 0.f : 1.f;
    const float mRf = (lane == 63) ? 0.f : 1.f;
    const float mTf = (x > 0) ? 1.f : 0.f;
    const float mBf = (x < 127) ? 1.f : 0.f;
    const int dT = (x > 0) ? -128 : 0;
    const int dB = (x < 127) ? 128 : 0;

    const size_t nbase = (size_t)b * NPIX + (size_t)x * 128;

    for (int chunk = 0; chunk < 4; ++chunk) {
        for (int g = 0; g < 4; ++g) {
            const int cl0 = w * 16 + g * 4;      // channel within chunk
            const int c0 = chunk * 64 + cl0;     // global channel
            float2 T[4], M[4], B[4];
            #pragma unroll
            for (int i = 0; i < 4; ++i) {
                const float* p = fmap + ((size_t)(b * 256 + c0 + i)) * NPIX + (size_t)x * 128;
                M[i] = ((const float2*)p)[lane];
                T[i] = ((const float2*)(p + dT))[lane];
                B[i] = ((const float2*)(p + dB))[lane];
            }
            #pragma unroll
            for (int i = 0; i < 4; ++i) {
                const float* wc = wdw + (c0 + i) * 9;  // block-uniform -> scalar loads
                float w0 = wc[0] * mTf, w1 = wc[1] * mTf, w2 = wc[2] * mTf;
                float w3 = wc[3],       w4 = wc[4],       w5 = wc[5];
                float w6 = wc[6] * mBf, w7 = wc[7] * mBf, w8 = wc[8] * mBf;
                float tL = __shfl_up(T[i].y, 1) * mLf;
                float mL_ = __shfl_up(M[i].y, 1) * mLf;
                float bL = __shfl_up(B[i].y, 1) * mLf;
                float tR = __shfl_down(T[i].x, 1) * mRf;
                float mR_ = __shfl_down(M[i].x, 1) * mRf;
                float bR = __shfl_down(B[i].x, 1) * mRf;
                float o0 = w0 * tL     + w1 * T[i].x + w2 * T[i].y
                         + w3 * mL_    + w4 * M[i].x + w5 * M[i].y
                         + w6 * bL     + w7 * B[i].x + w8 * B[i].y;
                float o1 = w0 * T[i].x + w1 * T[i].y + w2 * tR
                         + w3 * M[i].x + w4 * M[i].y + w5 * mR_
                         + w6 * B[i].x + w7 * B[i].y + w8 * bR;
                int cl = cl0 + i;
                dst[0][2 * lane][cl]     = f2bf(M[i].x);
                dst[0][2 * lane + 1][cl] = f2bf(M[i].y);
                dst[1][2 * lane][cl]     = f2bf(o0);
                dst[1][2 * lane + 1][cl] = f2bf(o1);
            }
        }
        __syncthreads();
        #pragma unroll
        for (int T2 = 0; T2 < 2; ++T2) {
            u16* gp = T2 ? dwT : fmapT;
            #pragma unroll
            for (int it = 0; it < 4; ++it) {
                int u = it * 256 + t;
                int y = u >> 3, c8 = (u & 7) * 8;
                const u16* s = &dst[T2][y][c8];
                uint4 val;
                val.x = *(const u32*)(s);
                val.y = *(const u32*)(s + 2);
                val.z = *(const u32*)(s + 4);
                val.w = *(const u32*)(s + 6);
                *(uint4*)(gp + (nbase + y) * 256 + chunk * 64 + c8) = val;
            }
        }
        __syncthreads();
    }
}

// ---------------- K2: kv projection GEMM; k-half -> exp -> E, v-half -> V ----------------
// D[m=ch 128][n=pix 128] = wpw[ch][c] * dwT[pix][c]^T, K=256
__global__ __launch_bounds__(256) void k_proj_kv(
    const u16* __restrict__ dwT, const u16* __restrict__ wpw,
    u16* __restrict__ E, u16* __restrict__ V)
{
    const int t = threadIdx.x;
    const int lane = t & 63, w = t >> 6;
    const int l15 = lane & 15, quad = lane >> 4;
    const int n0 = blockIdx.x * 128;
    const int o0 = blockIdx.y * 128;
    const int b  = blockIdx.z;
    __shared__ __align__(16) u16 sm[2 * 128 * 72];
    u16* As = sm;
    u16* Bs = sm + 128 * 72;
    f32x4 acc[4][4] = {};
    const int mh = (w >> 1) * 64, nh = (w & 1) * 64;
    const u16* wrow = wpw + (size_t)o0 * 256;
    const u16* xrow = dwT + ((size_t)b * NPIX + n0) * 256;
    for (int kc = 0; kc < 4; ++kc) {
        __syncthreads();
        const int g = t & 7;
        #pragma unroll
        for (int p = 0; p < 4; ++p) {
            int row = (t >> 3) + 32 * p;
            *(uint4*)(As + row * 72 + g * 8) = *(const uint4*)(wrow + (size_t)row * 256 + kc * 64 + g * 8);
            *(uint4*)(Bs + row * 72 + g * 8) = *(const uint4*)(xrow + (size_t)row * 256 + kc * 64 + g * 8);
        }
        __syncthreads();
        #pragma unroll
        for (int kk = 0; kk < 64; kk += 32) {
            bf16x8 av[4], bv[4];
            #pragma unroll
            for (int mf = 0; mf < 4; ++mf)
                av[mf] = *(const bf16x8*)(As + (mh + mf * 16 + l15) * 72 + kk + quad * 8);
            #pragma unroll
            for (int nf = 0; nf < 4; ++nf)
                bv[nf] = *(const bf16x8*)(Bs + (nh + nf * 16 + l15) * 72 + kk + quad * 8);
            #pragma unroll
            for (int mf = 0; mf < 4; ++mf)
                #pragma unroll
                for (int nf = 0; nf < 4; ++nf)
                    acc[mf][nf] = __builtin_amdgcn_mfma_f32_16x16x32_bf16(av[mf], bv[nf], acc[mf][nf], 0, 0, 0);
        }
    }
    __syncthreads();
    const bool isE = (o0 < 512);
    u16* ep = sm;  // [128][136]
    #pragma unroll
    for (int mf = 0; mf < 4; ++mf)
        #pragma unroll
        for (int nf = 0; nf < 4; ++nf)
            #pragma unroll
            for (int r = 0; r < 4; ++r) {
                int row = mh + mf * 16 + quad * 4 + r;
                int col = nh + nf * 16 + l15;
                float vv = acc[mf][nf][r];
                if (isE) vv = expf(vv);
                ep[row * 136 + col] = f2bf(vv);
            }
    __syncthreads();
    u16* outp = isE ? E : V;
    const int cb = isE ? o0 : (o0 - 512);
    for (int p = 0; p < 4; ++p) {
        int row = (t >> 3) + 32 * p;
        size_t base = ((size_t)b * 512 + cb + row) * NPIX + n0;
        int g2 = (t & 7) * 16;
        *(uint4*)(outp + base + g2)     = *(const uint4*)(ep + row * 136 + g2);
        *(uint4*)(outp + base + g2 + 8) = *(const uint4*)(ep + row * 136 + g2 + 8);
    }
}

// ---------------- K3: context ctxT[e][d] = sum_n V[e][n]*E[d][n] (split-K atomics) + denom ----------------
__global__ __launch_bounds__(256) void k_context(
    const u16* __restrict__ E, const u16* __restrict__ V,
    float* __restrict__ ctx, float* __restrict__ denom)
{
    const int t = threadIdx.x;
    const int lane = t & 63, w = t >> 6;
    const int l15 = lane & 15, quad = lane >> 4;
    const int nb = blockIdx.x * 512;
    const int bh = blockIdx.y;
    __shared__ __align__(16) u16 sm[2 * 64 * 136];
    u16* As = sm;
    u16* Bs = sm + 64 * 136;
    __shared__ float dsum[64];
    if (t < 64) dsum[t] = 0.f;
    f32x4 acc[4] = {};
    const u16* Vb = V + (size_t)bh * 64 * NPIX;
    const u16* Eb = E + (size_t)bh * 64 * NPIX;
    for (int cch = 0; cch < 4; ++cch) {
        int ns = nb + cch * 128;
        __syncthreads();
        int g = t & 15;
        #pragma unroll
        for (int p = 0; p < 4; ++p) {
            int row = (t >> 4) + 16 * p;
            *(uint4*)(As + row * 136 + g * 8) = *(const uint4*)(Vb + (size_t)row * NPIX + ns + g * 8);
            *(uint4*)(Bs + row * 136 + g * 8) = *(const uint4*)(Eb + (size_t)row * NPIX + ns + g * 8);
        }
        __syncthreads();
        #pragma unroll
        for (int kk = 0; kk < 128; kk += 32) {
            bf16x8 av = *(const bf16x8*)(As + (w * 16 + l15) * 136 + kk + quad * 8);
            #pragma unroll
            for (int nf = 0; nf < 4; ++nf) {
                bf16x8 bv = *(const bf16x8*)(Bs + (nf * 16 + l15) * 136 + kk + quad * 8);
                acc[nf] = __builtin_amdgcn_mfma_f32_16x16x32_bf16(av, bv, acc[nf], 0, 0, 0);
            }
        }
    }
    #pragma unroll
    for (int nf = 0; nf < 4; ++nf)
        #pragma unroll
        for (int r = 0; r < 4; ++r) {
            int e = w * 16 + quad * 4 + r;
            int d = nf * 16 + l15;
            atomicAdd(ctx + ((size_t)bh * 64 + e) * 64 + d, acc[nf][r]);
        }
    // denominator partials over this block's n-slice
    for (int d = 0; d < 64; ++d) {
        u32 u = *(const u32*)(Eb + (size_t)d * NPIX + nb + t * 2);
        float s = bf2f(u & 0xFFFFu) + bf2f(u >> 16);
        s += __shfl_xor(s, 1);  s += __shfl_xor(s, 2);  s += __shfl_xor(s, 4);
        s += __shfl_xor(s, 8);  s += __shfl_xor(s, 16); s += __shfl_xor(s, 32);
        if (lane == 0) atomicAdd(dsum + d, s);
    }
    __syncthreads();
    if (t < 64) atomicAdd(denom + bh * 64 + t, dsum[t]);
}

// ---------------- K1: q projection GEMM + fused per-(pixel,head) softmax * 1/8 ----------------
__global__ __launch_bounds__(256) void k_proj_q(
    const u16* __restrict__ fmapT, const u16* __restrict__ wq,
    u16* __restrict__ q)
{
    const int t = threadIdx.x;
    const int lane = t & 63, w = t >> 6;
    const int l15 = lane & 15, quad = lane >> 4;
    const int n0 = blockIdx.x * 128;
    const int o0 = blockIdx.y * 128;
    const int b  = blockIdx.z;
    __shared__ __align__(16) unsigned char smraw[71680];
    u16* As = (u16*)smraw;
    u16* Bs = As + 128 * 72;
    f32x4 acc[4][4] = {};
    const int mh = (w >> 1) * 64, nh = (w & 1) * 64;
    const u16* wrow = wq + (size_t)o0 * 256;
    const u16* xrow = fmapT + ((size_t)b * NPIX + n0) * 256;
    for (int kc = 0; kc < 4; ++kc) {
        __syncthreads();
        const int g = t & 7;
        #pragma unroll
        for (int p = 0; p < 4; ++p) {
            int row = (t >> 3) + 32 * p;
            *(uint4*)(As + row * 72 + g * 8) = *(const uint4*)(wrow + (size_t)row * 256 + kc * 64 + g * 8);
            *(uint4*)(Bs + row * 72 + g * 8) = *(const uint4*)(xrow + (size_t)row * 256 + kc * 64 + g * 8);
        }
        __syncthreads();
        #pragma unroll
        for (int kk = 0; kk < 64; kk += 32) {
            bf16x8 av[4], bv[4];
            #pragma unroll
            for (int mf = 0; mf < 4; ++mf)
                av[mf] = *(const bf16x8*)(As + (mh + mf * 16 + l15) * 72 + kk + quad * 8);
            #pragma unroll
            for (int nf = 0; nf < 4; ++nf)
                bv[nf] = *(const bf16x8*)(Bs + (nh + nf * 16 + l15) * 72 + kk + quad * 8);
            #pragma unroll
            for (int mf = 0; mf < 4; ++mf)
                #pragma unroll
                for (int nf = 0; nf < 4; ++nf)
                    acc[mf][nf] = __builtin_amdgcn_mfma_f32_16x16x32_bf16(av[mf], bv[nf], acc[mf][nf], 0, 0, 0);
        }
    }
    __syncthreads();
    float* ep = (float*)smraw;  // [128 pix][140] fp32 logits, transposed
    #pragma unroll
    for (int mf = 0; mf < 4; ++mf)
        #pragma unroll
        for (int nf = 0; nf < 4; ++nf)
            #pragma unroll
            for (int r = 0; r < 4; ++r) {
                int row = mh + mf * 16 + quad * 4 + r;  // local channel 0..127
                int col = nh + nf * 16 + l15;           // pixel
                ep[col * 140 + row] = acc[mf][nf][r];
            }
    __syncthreads();
    const int h0 = blockIdx.y * 2;
    for (int p = 0; p < 8; ++p) {
        int unit = p * 32 + (t >> 3);
        int pix = unit >> 1, hh = unit & 1;
        int d8 = (t & 7) * 8;
        f32x4 v0 = *(const f32x4*)(ep + pix * 140 + hh * 64 + d8);
        f32x4 v1 = *(const f32x4*)(ep + pix * 140 + hh * 64 + d8 + 4);
        float e0 = expf(v0[0]), e1 = expf(v0[1]), e2 = expf(v0[2]), e3 = expf(v0[3]);
        float e4 = expf(v1[0]), e5 = expf(v1[1]), e6 = expf(v1[2]), e7 = expf(v1[3]);
        float s = ((e0 + e1) + (e2 + e3)) + ((e4 + e5) + (e6 + e7));
        s += __shfl_xor(s, 1); s += __shfl_xor(s, 2); s += __shfl_xor(s, 4);
        float r = 0.125f / s;
        uint4 u;
        u.x = pk2(e0 * r, e1 * r); u.y = pk2(e2 * r, e3 * r);
        u.z = pk2(e4 * r, e5 * r); u.w = pk2(e6 * r, e7 * r);
        size_t off = (((size_t)b * 8 + h0 + hh) * NPIX + n0 + pix) * 64 + d8;
        *(uint4*)(q + off) = u;
    }
}

// ---------------- K4: out = (gelu(q @ ctx_norm)) @ w_out^T + b ----------------
__global__ __launch_bounds__(256) void k_attnout(
    const u16* __restrict__ q, const float* __restrict__ ctx,
    const float* __restrict__ denom, const u16* __restrict__ wout,
    const float* __restrict__ bout, float* __restrict__ out)
{
    const int t = threadIdx.x;
    const int lane = t & 63, w = t >> 6;
    const int l15 = lane & 15, quad = lane >> 4;
    const int n0 = blockIdx.x * 32;
    const int b  = blockIdx.y;
    __shared__ __align__(16) u16 tmp[32 * 520];
    __shared__ __align__(16) unsigned char R[20480];
    u16* qs = (u16*)R;            // [32][72]
    u16* cs = (u16*)(R + 4608);   // [64][72]
    u16* ws = (u16*)R;            // [256][40] (reused after head loop)
    for (int h = 0; h < 8; ++h) {
        __syncthreads();
        {
            int row = t >> 3, g = t & 7;
            *(uint4*)(qs + row * 72 + g * 8) =
                *(const uint4*)(q + (((size_t)b * 8 + h) * NPIX + n0 + row) * 64 + g * 8);
        }
        const int bh = b * 8 + h;
        #pragma unroll
        for (int p = 0; p < 4; ++p) {
            int idx = p * 256 + t;
            int e = idx >> 4, dq = (idx & 15) * 4;
            f32x4 c4 = *(const f32x4*)(ctx + ((size_t)bh * 64 + e) * 64 + dq);
            f32x4 d4 = *(const f32x4*)(denom + bh * 64 + dq);
            uint2 u;
            u.x = pk2(c4[0] / d4[0], c4[1] / d4[1]);
            u.y = pk2(c4[2] / d4[2], c4[3] / d4[3]);
            *(uint2*)(cs + e * 72 + dq) = u;
        }
        __syncthreads();
        f32x4 a1[2] = {};
        #pragma unroll
        for (int kk = 0; kk < 64; kk += 32) {
            bf16x8 av = *(const bf16x8*)(qs + ((w & 1) * 16 + l15) * 72 + kk + quad * 8);
            #pragma unroll
            for (int j = 0; j < 2; ++j) {
                int nf = (w >> 1) * 2 + j;
                bf16x8 bv = *(const bf16x8*)(cs + (nf * 16 + l15) * 72 + kk + quad * 8);
                a1[j] = __builtin_amdgcn_mfma_f32_16x16x32_bf16(av, bv, a1[j], 0, 0, 0);
            }
        }
        #pragma unroll
        for (int j = 0; j < 2; ++j)
            #pragma unroll
            for (int r = 0; r < 4; ++r) {
                int pix = (w & 1) * 16 + quad * 4 + r;
                int e = ((w >> 1) * 2 + j) * 16 + l15;
                float x = a1[j][r];
                float gel = 0.5f * x * (1.0f + erff(x * 0.70710678118654752f));
                tmp[pix * 520 + h * 64 + e] = f2bf(gel);
            }
    }
    __syncthreads();
    f32x4 acc[4][2] = {};
    for (int kc = 0; kc < 16; ++kc) {
        __syncthreads();
        #pragma unroll
        for (int p = 0; p < 4; ++p) {
            int c = (t >> 2) + 64 * p, g = t & 3;
            *(uint4*)(ws + c * 40 + g * 8) = *(const uint4*)(wout + (size_t)c * 512 + kc * 32 + g * 8);
        }
        __syncthreads();
        bf16x8 av[4], bv[2];
        #pragma unroll
        for (int mf = 0; mf < 4; ++mf)
            av[mf] = *(const bf16x8*)(ws + (w * 64 + mf * 16 + l15) * 40 + quad * 8);
        #pragma unroll
        for (int nf = 0; nf < 2; ++nf)
            bv[nf] = *(const bf16x8*)(tmp + (nf * 16 + l15) * 520 + kc * 32 + quad * 8);
        #pragma unroll
        for (int mf = 0; mf < 4; ++mf)
            #pragma unroll
            for (int nf = 0; nf < 2; ++nf)
                acc[mf][nf] = __builtin_amdgcn_mfma_f32_16x16x32_bf16(av[mf], bv[nf], acc[mf][nf], 0, 0, 0);
    }
    #pragma unroll
    for (int mf = 0; mf < 4; ++mf)
        #pragma unroll
        for (int nf = 0; nf < 2; ++nf)
            #pragma unroll
            for (int r = 0; r < 4; ++r) {
                int c = w * 64 + mf * 16 + quad * 4 + r;
                int pix = nf * 16 + l15;
                out[((size_t)b * 256 + c) * NPIX + n0 + pix] = acc[mf][nf][r] + bout[c];
            }
}

extern "C" void kernel_launch(void* const* d_in, const int* in_sizes, int n_in,
                              void* d_out, int out_size, void* d_ws, size_t ws_size,
                              hipStream_t stream)
{
    const float* fmap  = (const float*)d_in[0];
    const float* w_q   = (const float*)d_in[1];
    const float* w_dw  = (const float*)d_in[2];
    const float* w_pw  = (const float*)d_in[3];
    const float* w_out = (const float*)d_in[4];
    const float* b_out = (const float*)d_in[5];
    float* out = (float*)d_out;
    char* ws = (char*)d_ws;

    u16* dwT     = (u16*)(ws);                  // 67,108,864 B  [8][16384][256]
    u16* fmapT   = (u16*)(ws + 67108864);       // 67,108,864 B
    u16* E       = (u16*)(ws + 134217728);      // 134,217,728 B [8][512][16384]
    u16* V       = (u16*)(ws + 268435456);      // 134,217,728 B
    u16* q       = (u16*)(ws + 134217728);      // overlaps E (dead after k_context)
    float* ctx   = (float*)(ws + 402653184);    // 1,048,576 B  [64][64][64]
    float* denom = (float*)(ws + 403701760);    // 16,384 B
    u16* wq_b    = (u16*)(ws + 403718144);      // 262,144 B
    u16* wpw_b   = (u16*)(ws + 403980288);      // 524,288 B
    u16* wout_b  = (u16*)(ws + 404504576);      // 262,144 B
    // total workspace: 404,766,720 B

    hipMemsetAsync(ws + 402653184, 0, 1048576 + 16384, stream);
    k_cvtw<<<512, 256, 0, stream>>>(w_q, w_pw, w_out, wq_b, wpw_b, wout_b);
    k_conv<<<dim3(128, 8), 256, 0, stream>>>(fmap, w_dw, fmapT, dwT);
    k_proj_kv<<<dim3(128, 8, 8), 256, 0, stream>>>(dwT, wpw_b, E, V);
    k_context<<<dim3(32, 64), 256, 0, stream>>>(E, V, ctx, denom);
    k_proj_q<<<dim3(128, 4, 8), 256, 0, stream>>>(fmapT, wq_b, q);  // q overlaps E: must run after k_context
    k_attnout<<<dim3(512, 8), 256, 0, stream>>>(q, ctx, denom, wout_b, b_out, out);
}